// Round 3
// baseline (44.959 us; speedup 1.0000x reference)
//
#include <hip/hip_runtime.h>

// CycleFC spatial shift along W (DIM==3), SHIFT_SIZE=5 -> PAD=2.
// x: [B=32, C=256, H=64, W=64] f32, NCHW contiguous.
// shift[c] = base[c % 8], base = {-2,-1,0,1,2,1,0,-1}
// out[b,c,h,w] = (0 <= w - s < 64) ? x[b,c,h,w-s] : 0
//
// R2: same nontemporal-store experiment as R1, but with a native clang
// vector type (ext_vector_type) — __builtin_nontemporal_store rejects
// HIP_vector_type structs. Goal: keep the 134 MB write stream from
// evicting the L3-resident input across timed replays.

typedef float f32x4 __attribute__((ext_vector_type(4)));

__global__ __launch_bounds__(256) void cyclefc_shift_w(
    const float* __restrict__ x, float* __restrict__ y, int nvec)
{
    int idx = blockIdx.x * blockDim.x + threadIdx.x;
    if (idx >= nvec) return;

    // W=64 -> 16 float4 per row; row = b*C*H + c*H + h
    int w0  = (idx & 15) << 2;
    int row = idx >> 4;
    int c   = (row >> 6) & 255;          // (row / H) % C, H=64, C=256
    int k   = c & 7;
    int s   = (int)((0x12343210u >> (k << 2)) & 0xFu) - 2;

    const float* xr = x + ((size_t)row << 6);   // row base, 64 floats
    int sw = w0 - s;                             // source w for lane's first elem

    f32x4 o;
    o.x = ((unsigned)(sw    ) < 64u) ? xr[sw    ] : 0.0f;
    o.y = ((unsigned)(sw + 1) < 64u) ? xr[sw + 1] : 0.0f;
    o.z = ((unsigned)(sw + 2) < 64u) ? xr[sw + 2] : 0.0f;
    o.w = ((unsigned)(sw + 3) < 64u) ? xr[sw + 3] : 0.0f;

    __builtin_nontemporal_store(o, reinterpret_cast<f32x4*>(y) + idx);
}

extern "C" void kernel_launch(void* const* d_in, const int* in_sizes, int n_in,
                              void* d_out, int out_size, void* d_ws, size_t ws_size,
                              hipStream_t stream) {
    const float* x = (const float*)d_in[0];
    float* y = (float*)d_out;

    int nvec = out_size >> 2;                    // 33554432 / 4 = 8388608
    int threads = 256;
    int blocks = (nvec + threads - 1) / threads; // 32768
    cyclefc_shift_w<<<blocks, threads, 0, stream>>>(x, y, nvec);
}

// Round 4
// 43.436 us; speedup vs baseline: 1.0351x; 1.0351x over previous
//
#include <hip/hip_runtime.h>

// CycleFC spatial shift along W (DIM==3), SHIFT_SIZE=5 -> PAD=2.
// x: [B=32, C=256, H=64, W=64] f32, NCHW contiguous.
// shift[c] = base[c % 8], base = {-2,-1,0,1,2,1,0,-1}
// out[b,c,h,w] = (0 <= w - s < 64) ? x[b,c,h,w-s] : 0
//
// FINAL (R0 revert): pure streaming permutation, one thread per float4.
// 268.4 MB total HBM traffic @ ~6.17 TB/s = 98% of the measured 6.29 TB/s
// copy ceiling. nt-store experiment (R3) was neutral/negative — MALL is
// memory-side; reads cannot be converted to L3 hits. This is the roofline.

__global__ __launch_bounds__(256) void cyclefc_shift_w(
    const float* __restrict__ x, float* __restrict__ y, int nvec)
{
    int idx = blockIdx.x * blockDim.x + threadIdx.x;
    if (idx >= nvec) return;

    // W=64 -> 16 float4 per row; row = b*C*H + c*H + h
    int w0  = (idx & 15) << 2;
    int row = idx >> 4;
    int c   = (row >> 6) & 255;          // (row / H) % C, H=64, C=256
    int k   = c & 7;
    int s   = (int)((0x12343210u >> (k << 2)) & 0xFu) - 2;

    const float* xr = x + ((size_t)row << 6);   // row base, 64 floats
    int sw = w0 - s;                             // source w for lane's first elem

    float4 o;
    o.x = ((unsigned)(sw    ) < 64u) ? xr[sw    ] : 0.0f;
    o.y = ((unsigned)(sw + 1) < 64u) ? xr[sw + 1] : 0.0f;
    o.z = ((unsigned)(sw + 2) < 64u) ? xr[sw + 2] : 0.0f;
    o.w = ((unsigned)(sw + 3) < 64u) ? xr[sw + 3] : 0.0f;

    reinterpret_cast<float4*>(y)[idx] = o;
}

extern "C" void kernel_launch(void* const* d_in, const int* in_sizes, int n_in,
                              void* d_out, int out_size, void* d_ws, size_t ws_size,
                              hipStream_t stream) {
    const float* x = (const float*)d_in[0];
    float* y = (float*)d_out;

    int nvec = out_size >> 2;                    // 33554432 / 4 = 8388608
    int threads = 256;
    int blocks = (nvec + threads - 1) / threads; // 32768
    cyclefc_shift_w<<<blocks, threads, 0, stream>>>(x, y, nvec);
}